// Round 5
// baseline (75.065 us; speedup 1.0000x reference)
//
#include <hip/hip_runtime.h>
#include <math.h>

// TropConv2D: out[b,ho,wo,f] = max_k(patch + w) - min_k(patch + w) + bias
// B=8, H=W=32, C=32, KH=KW=3, F=64, Ho=Wo=30, K=288. 7200 output pixels.
//
// R7 theory: R4/R6's s_load x path is lgkm-POISON. SMEM retires
// out-of-order, so every s_load consumption forces lgkmcnt(0), which
// drains all in-flight ds_reads too -> one full memory round-trip per
// inner iteration, no MLP. Fix: x through VMEM (vmcnt counter,
// independent of lgkm) so ds_read w (lgkm) and x loads (vmcnt) both
// stay deeply pipelined.
//
// Structure:
//  * w[k][f] LINEAR in LDS, staged once with coalesced conflict-free
//    float4 copies (R5's transposed scatter = 8-way write conflicts;
//    never again). ONE barrier per block.
//  * x: per-pixel VGPR pointers, float4 VMEM loads (wave-uniform
//    address -> 1 cache line broadcast, L1-resident working set).
//  * PIX=4, TPB=512 (8 waves): 225 blocks = exactly <=1 block/CU,
//    single round, no 2-round imbalance. DS ops amortized over 4
//    pixels: 288 ds_read/wave for 4 pixels of output.
//  * max3/min3 reassociation (v_max3_f32 / v_min3_f32).
// Per-CU model: DS ~5.6us, VMEM issue ~3.8us, VALU ~4.3us, overlapped.

#define TPB 512  // 8 waves
#define PIX 4

__device__ __forceinline__ float fmax3(float a, float b, float c) {
    return fmaxf(fmaxf(a, b), c);
}
__device__ __forceinline__ float fmin3(float a, float b, float c) {
    return fminf(fminf(a, b), c);
}

__global__ __launch_bounds__(TPB) void trop_kernel(
    const float* __restrict__ x,     // (8,32,32,32)
    const float* __restrict__ w,     // (288,64) = 9 taps * (32,64)
    const float* __restrict__ bias,  // (64,)
    float* __restrict__ out)         // (8,30,30,64) = (7200,64)
{
    extern __shared__ float wlds[];  // 18432 floats = 72 KiB, w[k][f] linear

    const int tid  = threadIdx.x;
    const int lane = tid & 63;
    const int wv   = tid >> 6;

    const int pix0 = blockIdx.x * (8 * PIX) + wv * PIX;  // 0..7196

    // Stage ALL of w: 4608 float4 across 512 threads = 9 each.
    // Coalesced global float4; LDS writes lane-consecutive -> conflict-free.
    {
        const float4* src = (const float4*)w;
        float4* dst = (float4*)wlds;
#pragma unroll
        for (int i = 0; i < 9; ++i) dst[tid + i * 512] = src[tid + i * 512];
    }

    // Per-pixel x base pointers. Deliberately NOT readfirstlane'd:
    // keep these as VGPR addresses so x loads stay VMEM (vmcnt), not
    // SMEM (lgkm) -- mixing s_load with ds_read serializes on lgkmcnt(0).
    const float* xp[PIX];
#pragma unroll
    for (int p = 0; p < PIX; ++p) {
        const int pid = pix0 + p;
        const int wo = pid % 30;
        const int t  = pid / 30;
        const int ho = t % 30;
        const int b  = t / 30;
        xp[p] = x + (((b * 32 + ho) * 32) + wo) * 32;
    }

    float amax[PIX], amin[PIX];
#pragma unroll
    for (int p = 0; p < PIX; ++p) { amax[p] = -INFINITY; amin[p] = INFINITY; }

    __syncthreads();  // the only barrier

#pragma unroll
    for (int tap = 0; tap < 9; ++tap) {
        const int dy = tap / 3;
        const int dx = tap % 3;
        const int xoff = (dy * 32 + dx) * 32;
        const float* wl = wlds + tap * 2048;
#pragma unroll
        for (int c = 0; c < 32; c += 4) {
            const float w0 = wl[(c + 0) * 64 + lane];
            const float w1 = wl[(c + 1) * 64 + lane];
            const float w2 = wl[(c + 2) * 64 + lane];
            const float w3 = wl[(c + 3) * 64 + lane];
#pragma unroll
            for (int p = 0; p < PIX; ++p) {
                const float4 xv = *(const float4*)(xp[p] + xoff + c);  // VMEM, wave-uniform
                const float s0 = xv.x + w0;
                const float s1 = xv.y + w1;
                const float s2 = xv.z + w2;
                const float s3 = xv.w + w3;
                amax[p] = fmax3(amax[p], fmax3(s0, s1, s2), s3);
                amin[p] = fmin3(amin[p], fmin3(s0, s1, s2), s3);
            }
        }
    }

    const float bv = bias[lane];
#pragma unroll
    for (int p = 0; p < PIX; ++p)
        out[(pix0 + p) * 64 + lane] = amax[p] - amin[p] + bv;
}

extern "C" void kernel_launch(void* const* d_in, const int* in_sizes, int n_in,
                              void* d_out, int out_size, void* d_ws, size_t ws_size,
                              hipStream_t stream) {
    const float* x    = (const float*)d_in[0];
    const float* w    = (const float*)d_in[1];
    const float* bias = (const float*)d_in[2];
    float* out = (float*)d_out;

    // 72 KiB dynamic LDS; 1 block/CU resident here (225 blocks / 256 CU).
    static int attr_done = 0;
    if (!attr_done) {
        (void)hipFuncSetAttribute((const void*)trop_kernel,
                                  hipFuncAttributeMaxDynamicSharedMemorySize,
                                  73728);
        attr_done = 1;
    }

    // 7200 pixels / (8 waves * 4 pixels) = 225 blocks
    trop_kernel<<<dim3(225), dim3(TPB), 73728, stream>>>(x, w, bias, out);
}